// Round 5
// baseline (149.276 us; speedup 1.0000x reference)
//
#include <hip/hip_runtime.h>
#include <hip/hip_bf16.h>

#define B_N 16
#define S_LEN 2048
#define D_DIM 128
#define TK 32
#define NTH 32            // key tiles per group (2 groups x 32 x 32 = 2048 keys)

typedef __attribute__((ext_vector_type(16))) float f32x16;
typedef __attribute__((ext_vector_type(8)))  short short8;
typedef const __attribute__((address_space(1))) void* gp1;
typedef __attribute__((address_space(3))) void* sp3;
#define GLL(g, l) __builtin_amdgcn_global_load_lds((gp1)(const void*)(g), (sp3)(void*)(l), 16, 0, 0)

static __device__ __forceinline__ unsigned short f2bf(float f) {
  unsigned u = __builtin_bit_cast(unsigned, f);
  return (unsigned short)((u + 0x7fffu + ((u >> 16) & 1u)) >> 16);  // RNE
}

static __device__ __forceinline__ unsigned pk_bf16(float a, float b) {
#if __has_builtin(__builtin_amdgcn_cvt_pk_bf16_f32)
  typedef __attribute__((ext_vector_type(2))) __bf16 bf16x2;
  bf16x2 r = __builtin_amdgcn_cvt_pk_bf16_f32(a, b);
  return __builtin_bit_cast(unsigned, r);
#else
  return (unsigned)f2bf(a) | ((unsigned)f2bf(b) << 16);
#endif
}

// ---------------- prepass: K -> bf16 row-major; V -> bf16 transposed [b][d][s] ----------------
__global__ __launch_bounds__(256)
void prep_kernel(const float* __restrict__ K, const float* __restrict__ V,
                 unsigned short* __restrict__ Kb, unsigned short* __restrict__ VT) {
  __shared__ unsigned short lds[64 * 66];
  int bx = blockIdx.x;
  int t  = threadIdx.x;
  if (bx < 4096) {
    size_t i = ((size_t)bx * 256 + t) * 4;
    float4 v = *(const float4*)(K + i);
    *(uint2*)(Kb + i) = make_uint2(pk_bf16(v.x, v.y), pk_bf16(v.z, v.w));
  } else {
    int bi = bx - 4096;                 // 1024 = 16 b x 32 st x 2 dt
    int b  = bi & 15;
    int st = (bi >> 4) & 31;
    int dt = bi >> 9;
    const float* Vb = V + ((size_t)b * S_LEN + st * 64) * D_DIM + dt * 64;
    unsigned short* VTb = VT + ((size_t)b * D_DIM + dt * 64) * S_LEN + st * 64;
#pragma unroll
    for (int rep = 0; rep < 4; ++rep) {
      int idx = rep * 256 + t;
      int i  = idx >> 4;                // s-local 0..63
      int j4 = (idx & 15) * 4;          // d-local
      float4 v = *(const float4*)(Vb + (size_t)i * D_DIM + j4);
      *(uint2*)&lds[i * 66 + j4] = make_uint2(pk_bf16(v.x, v.y), pk_bf16(v.z, v.w));
    }
    __syncthreads();
#pragma unroll
    for (int rep = 0; rep < 4; ++rep) {
      int idx = rep * 256 + t;
      int dd = idx >> 4;                // d-local 0..63
      int s4 = (idx & 15) * 4;          // s-local
      unsigned short e0 = lds[(s4 + 0) * 66 + dd];
      unsigned short e1 = lds[(s4 + 1) * 66 + dd];
      unsigned short e2 = lds[(s4 + 2) * 66 + dd];
      unsigned short e3 = lds[(s4 + 3) * 66 + dd];
      *(uint2*)(VTb + (size_t)dd * S_LEN + s4) =
          make_uint2((unsigned)e0 | ((unsigned)e1 << 16),
                     (unsigned)e2 | ((unsigned)e3 << 16));
    }
  }
}

// ---------------- main attention kernel: 512 thr, split-K across wave groups ----------------
__global__ __launch_bounds__(512, 2)
void attn_kernel(const float* __restrict__ Q, const unsigned short* __restrict__ Kb,
                 const unsigned short* __restrict__ VT, float* __restrict__ O) {
  // [0,32768) kbuf[g][buf][8192B] | [32768,65536) vbuf | merge overlay w4*16512 (O+l)
  __shared__ __align__(16) char smem[66048];

  const int tid  = threadIdx.x;
  const int wave = tid >> 6;
  const int g    = wave >> 2;           // key-half group
  const int w4   = wave & 3;            // q-row-group within block
  const int lane = tid & 63;
  const int l32  = lane & 31;
  const int half = lane >> 5;

  const int i     = blockIdx.x;
  const int b     = (i & 7) * 2 + ((i >> 3) & 1);   // XCD swizzle
  const int qtile = i >> 4;
  const int qbase = qtile * 128 + w4 * 32;

  const float* Qb = Q + (size_t)b * S_LEN * D_DIM;
  const unsigned short* Kbb = Kb + (size_t)b * S_LEN * D_DIM;
  const unsigned short* VTb = VT + (size_t)b * D_DIM * S_LEN;

  unsigned short* kb0 = (unsigned short*)smem + g * 8192;              // 2 bufs x 4096 sh
  unsigned short* vb0 = (unsigned short*)(smem + 32768) + g * 8192;

  // ---- DMA pointers (hoisted): running global ptrs + fixed LDS dsts ----
  const unsigned short* kgp[2];
  const unsigned short* vgp[2];
  unsigned short* kdst[2][2];
  unsigned short* vdst[2][2];
#pragma unroll
  for (int cc = 0; cc < 2; ++cc) {
    int c  = w4 * 2 + cc;
    int rl = 4 * c + (lane >> 4);
    int lbk = (lane & 15) ^ (rl & 15);
    kgp[cc] = Kbb + (size_t)(g * NTH * TK + rl) * D_DIM + lbk * 8;
    int dv = 16 * c + (lane >> 2);
    int lbv = (lane & 3) ^ ((dv >> 1) & 3);
    vgp[cc] = VTb + (size_t)dv * S_LEN + g * NTH * TK + lbv * 8;
    kdst[0][cc] = kb0 + c * 512;  kdst[1][cc] = kb0 + 4096 + c * 512;
    vdst[0][cc] = vb0 + c * 512;  vdst[1][cc] = vb0 + 4096 + c * 512;
  }
  // tile 0 DMA
#pragma unroll
  for (int cc = 0; cc < 2; ++cc) { GLL(kgp[cc], kdst[0][cc]); GLL(vgp[cc], vdst[0][cc]); }

  // ---- LDS read byte-offsets (hoisted) ----
  int kOff[8], vOff[8];
#pragma unroll
  for (int ks = 0; ks < 8; ++ks)
    kOff[ks] = (l32 * D_DIM + (((ks << 1) + half) ^ (l32 & 15)) * 8) * 2;
#pragma unroll
  for (int ks2 = 0; ks2 < 2; ++ks2)
#pragma unroll
    for (int dt = 0; dt < 4; ++dt) {
      int dv = dt * 32 + l32;
      int pv = ((ks2 << 1) + half) ^ ((dv >> 1) & 3);
      vOff[ks2 * 4 + dt] = (dv * TK + pv * 8) * 2;
    }

  // ---- Q fragments, pre-scaled by 1/sqrt(d)*log2(e), bf16 once ----
  const float SC = 0.08838834764831845f * 1.4426950408889634f;
  short8 qa[8];
  {
    const float* qp = Qb + (size_t)(qbase + l32) * D_DIM + half * 8;
#pragma unroll
    for (int ks = 0; ks < 8; ++ks) {
      float4 a0 = *(const float4*)(qp + ks * 16);
      float4 a1 = *(const float4*)(qp + ks * 16 + 4);
      union { unsigned u[4]; short8 s; } pu;
      pu.u[0] = pk_bf16(a0.x * SC, a0.y * SC);
      pu.u[1] = pk_bf16(a0.z * SC, a0.w * SC);
      pu.u[2] = pk_bf16(a1.x * SC, a1.y * SC);
      pu.u[3] = pk_bf16(a1.z * SC, a1.w * SC);
      qa[ks] = pu.s;
    }
  }

  const f32x16 zf16 = {0.f,0.f,0.f,0.f,0.f,0.f,0.f,0.f,0.f,0.f,0.f,0.f,0.f,0.f,0.f,0.f};
  f32x16 oacc[4];
#pragma unroll
  for (int dt = 0; dt < 4; ++dt) oacc[dt] = zf16;
  float lp[4] = {0.f, 0.f, 0.f, 0.f};

  for (int t = 0; t < NTH; ++t) {
    __syncthreads();  // drains DMA(t); frees buf (t+1)&1
    const int cb = t & 1;
    const char* kbc = (const char*)kb0 + cb * 8192;
    const char* vbc = (const char*)vb0 + cb * 8192;

    if (t + 1 < NTH) {  // DMA(t+1) flies during compute(t)
      const int nb = cb ^ 1;
#pragma unroll
      for (int cc = 0; cc < 2; ++cc) {
        kgp[cc] += TK * D_DIM;  GLL(kgp[cc], kdst[nb][cc]);
        vgp[cc] += TK;          GLL(vgp[cc], vdst[nb][cc]);
      }
    }

    // ---- S^T = K Q^T (regs = keys, cols = q) ----
    f32x16 sacc = zf16;
#pragma unroll
    for (int ks = 0; ks < 8; ++ks) {
      short8 kf = *(const short8*)(kbc + kOff[ks]);
      sacc = __builtin_amdgcn_mfma_f32_32x32x16_bf16(kf, qa[ks], sacc, 0, 0, 0);
    }

    // ---- max-free softmax: p = exp2(s) (scale folded into Q); pack to bf16 ----
    float p[16];
#pragma unroll
    for (int r = 0; r < 16; ++r) p[r] = exp2f(sacc[r]);
#pragma unroll
    for (int r = 0; r < 16; ++r) lp[r & 3] += p[r];
    unsigned w[8];
#pragma unroll
    for (int j = 0; j < 8; ++j) w[j] = pk_bf16(p[2 * j], p[2 * j + 1]);

    // ---- P^T -> A-layout via half-swap (no LDS round-trip) + O += P V ----
#pragma unroll
    for (int ks2 = 0; ks2 < 2; ++ks2) {
      const int a = ks2 * 4;
      unsigned x0 = (unsigned)__shfl_xor((int)w[a + 0], 32);
      unsigned x1 = (unsigned)__shfl_xor((int)w[a + 1], 32);
      unsigned x2 = (unsigned)__shfl_xor((int)w[a + 2], 32);
      unsigned x3 = (unsigned)__shfl_xor((int)w[a + 3], 32);
      union { unsigned u[4]; short8 s; } pu;
      pu.u[0] = half ? x2 : w[a + 0];
      pu.u[1] = half ? x3 : w[a + 1];
      pu.u[2] = half ? w[a + 2] : x0;
      pu.u[3] = half ? w[a + 3] : x1;
      short8 pf = pu.s;
#pragma unroll
      for (int dt = 0; dt < 4; ++dt) {
        short8 vf = *(const short8*)(vbc + vOff[ks2 * 4 + dt]);
        oacc[dt] = __builtin_amdgcn_mfma_f32_32x32x16_bf16(pf, vf, oacc[dt], 0, 0, 0);
      }
    }
  }

  // ---- per-lane row sum (q = l32): combine partials + cross-half ----
  float lt = (lp[0] + lp[1]) + (lp[2] + lp[3]);
  lt += __shfl_xor(lt, 32);

  // ---- split-K merge: group 1 -> LDS, group 0 adds, normalizes, stores ----
  __syncthreads();  // all tile reads done; safe to overlay merge region
  float* mo = (float*)(smem + w4 * 16512);
  float* ml = (float*)(smem + w4 * 16512 + 16384);
  if (g == 1) {
#pragma unroll
    for (int reg = 0; reg < 16; ++reg) {
      int row = (reg & 3) + 8 * (reg >> 2) + 4 * half;
#pragma unroll
      for (int dt = 0; dt < 4; ++dt)
        mo[row * 128 + dt * 32 + l32] = oacc[dt][reg];
    }
    if (half == 0) ml[l32] = lt;
  }
  __syncthreads();
  if (g == 0) {
    float tot = lt + ml[l32];
    float* Ob = O + (size_t)b * S_LEN * D_DIM;
#pragma unroll
    for (int reg = 0; reg < 16; ++reg) {
      int row = (reg & 3) + 8 * (reg >> 2) + 4 * half;
      float linv = 1.f / __shfl(tot, row);
#pragma unroll
      for (int dt = 0; dt < 4; ++dt)
        Ob[(size_t)(qbase + row) * D_DIM + dt * 32 + l32] =
            (oacc[dt][reg] + mo[row * 128 + dt * 32 + l32]) * linv;
    }
  }
}

extern "C" void kernel_launch(void* const* d_in, const int* in_sizes, int n_in,
                              void* d_out, int out_size, void* d_ws, size_t ws_size,
                              hipStream_t stream) {
  const float* Q = (const float*)d_in[0];
  const float* K = (const float*)d_in[1];
  const float* V = (const float*)d_in[2];
  float* O = (float*)d_out;
  unsigned short* Kb = (unsigned short*)d_ws;                       // 8.4 MB
  unsigned short* VT = Kb + (size_t)B_N * S_LEN * D_DIM;            // 8.4 MB
  prep_kernel<<<dim3(4096 + 1024), dim3(256), 0, stream>>>(K, V, Kb, VT);
  attn_kernel<<<dim3(256), dim3(512), 0, stream>>>(Q, Kb, VT, O);
}

// Round 6
// 148.084 us; speedup vs baseline: 1.0081x; 1.0081x over previous
//
#include <hip/hip_runtime.h>
#include <hip/hip_bf16.h>

#define B_N 16
#define S_LEN 2048
#define D_DIM 128
#define TK 32

typedef __attribute__((ext_vector_type(16))) float f32x16;
typedef __attribute__((ext_vector_type(8)))  short short8;
typedef const __attribute__((address_space(1))) void* gp1;
typedef __attribute__((address_space(3))) void* sp3;
#define GLL(g, l) __builtin_amdgcn_global_load_lds((gp1)(const void*)(g), (sp3)(void*)(l), 16, 0, 0)

static __device__ __forceinline__ unsigned short f2bf(float f) {
  unsigned u = __builtin_bit_cast(unsigned, f);
  return (unsigned short)((u + 0x7fffu + ((u >> 16) & 1u)) >> 16);  // RNE
}

static __device__ __forceinline__ unsigned pk_bf16(float a, float b) {
#if __has_builtin(__builtin_amdgcn_cvt_pk_bf16_f32)
  typedef __attribute__((ext_vector_type(2))) __bf16 bf16x2;
  bf16x2 r = __builtin_amdgcn_cvt_pk_bf16_f32(a, b);
  return __builtin_bit_cast(unsigned, r);
#else
  return (unsigned)f2bf(a) | ((unsigned)f2bf(b) << 16);
#endif
}

// ---------------- prepass: K -> bf16 row-major; V -> bf16 transposed [b][d][s] ----------------
__global__ __launch_bounds__(256)
void prep_kernel(const float* __restrict__ K, const float* __restrict__ V,
                 unsigned short* __restrict__ Kb, unsigned short* __restrict__ VT) {
  __shared__ unsigned short lds[64 * 66];
  int bx = blockIdx.x;
  int t  = threadIdx.x;
  if (bx < 4096) {
    size_t i = ((size_t)bx * 256 + t) * 4;
    float4 v = *(const float4*)(K + i);
    *(uint2*)(Kb + i) = make_uint2(pk_bf16(v.x, v.y), pk_bf16(v.z, v.w));
  } else {
    int bi = bx - 4096;                 // 1024 = 16 b x 32 st x 2 dt
    int b  = bi & 15;
    int st = (bi >> 4) & 31;
    int dt = bi >> 9;
    const float* Vb = V + ((size_t)b * S_LEN + st * 64) * D_DIM + dt * 64;
    unsigned short* VTb = VT + ((size_t)b * D_DIM + dt * 64) * S_LEN + st * 64;
#pragma unroll
    for (int rep = 0; rep < 4; ++rep) {
      int idx = rep * 256 + t;
      int i  = idx >> 4;                // s-local 0..63
      int j4 = (idx & 15) * 4;          // d-local
      float4 v = *(const float4*)(Vb + (size_t)i * D_DIM + j4);
      *(uint2*)&lds[i * 66 + j4] = make_uint2(pk_bf16(v.x, v.y), pk_bf16(v.z, v.w));
    }
    __syncthreads();
#pragma unroll
    for (int rep = 0; rep < 4; ++rep) {
      int idx = rep * 256 + t;
      int dd = idx >> 4;                // d-local 0..63
      int s4 = (idx & 15) * 4;          // s-local
      unsigned short e0 = lds[(s4 + 0) * 66 + dd];
      unsigned short e1 = lds[(s4 + 1) * 66 + dd];
      unsigned short e2 = lds[(s4 + 2) * 66 + dd];
      unsigned short e3 = lds[(s4 + 3) * 66 + dd];
      *(uint2*)(VTb + (size_t)dd * S_LEN + s4) =
          make_uint2((unsigned)e0 | ((unsigned)e1 << 16),
                     (unsigned)e2 | ((unsigned)e3 << 16));
    }
  }
}

// -------- main kernel: 768 thr = 4 q-groups x 3 key-groups, 12 waves/CU --------
__global__ __launch_bounds__(768, 3)
void attn_kernel(const float* __restrict__ Q, const unsigned short* __restrict__ Kb,
                 const unsigned short* __restrict__ VT, float* __restrict__ O) {
  // tiles: kbuf kg*16384 (2 bufs x 8192B) | vbuf 49152 + kg*16384
  // merge overlay (post-loop): 8 O-slots x 16KB at 0 + larr 1KB at 131072
  __shared__ __align__(16) char smem[132096];

  const int tid  = threadIdx.x;
  const int wave = tid >> 6;
  const int qg   = wave & 3;            // q-row group (32 rows)
  const int kg   = wave >> 2;           // key group: 0..2
  const int lane = tid & 63;
  const int l32  = lane & 31;
  const int half = lane >> 5;

  const int NK  = (kg == 0) ? 22 : 21;             // tiles for this key group
  const int KB0 = (kg == 0) ? 0 : 704 + (kg - 1) * 672;  // first key

  const int i     = blockIdx.x;
  const int b     = (i & 7) * 2 + ((i >> 3) & 1);  // XCD swizzle
  const int qtile = i >> 4;
  const int qbase = qtile * 128 + qg * 32;

  const float* Qb = Q + (size_t)b * S_LEN * D_DIM;
  const unsigned short* Kbb = Kb + (size_t)b * S_LEN * D_DIM;
  const unsigned short* VTb = VT + (size_t)b * D_DIM * S_LEN;

  char* kbase = smem + kg * 16384;
  char* vbase = smem + 49152 + kg * 16384;

  // ---- DMA pointers: running global ptrs + fixed LDS dsts ----
  const unsigned short* kgp[2];
  const unsigned short* vgp[2];
  unsigned short* kdst[2][2];
  unsigned short* vdst[2][2];
#pragma unroll
  for (int cc = 0; cc < 2; ++cc) {
    int c  = qg * 2 + cc;
    int rl = 4 * c + (lane >> 4);
    int lbk = (lane & 15) ^ (rl & 15);
    kgp[cc] = Kbb + (size_t)(KB0 + rl) * D_DIM + lbk * 8;
    int dv = 16 * c + (lane >> 2);
    int lbv = (lane & 3) ^ ((dv >> 1) & 3);
    vgp[cc] = VTb + (size_t)dv * S_LEN + KB0 + lbv * 8;
    kdst[0][cc] = (unsigned short*)kbase + c * 512;
    kdst[1][cc] = (unsigned short*)(kbase + 8192) + c * 512;
    vdst[0][cc] = (unsigned short*)vbase + c * 512;
    vdst[1][cc] = (unsigned short*)(vbase + 8192) + c * 512;
  }
  // tile 0 DMA
#pragma unroll
  for (int cc = 0; cc < 2; ++cc) { GLL(kgp[cc], kdst[0][cc]); GLL(vgp[cc], vdst[0][cc]); }

  // ---- LDS read byte-offsets (hoisted) ----
  int kOff[8], vOff[8];
#pragma unroll
  for (int ks = 0; ks < 8; ++ks)
    kOff[ks] = (l32 * D_DIM + (((ks << 1) + half) ^ (l32 & 15)) * 8) * 2;
#pragma unroll
  for (int ks2 = 0; ks2 < 2; ++ks2)
#pragma unroll
    for (int dt = 0; dt < 4; ++dt) {
      int dv = dt * 32 + l32;
      int pv = ((ks2 << 1) + half) ^ ((dv >> 1) & 3);
      vOff[ks2 * 4 + dt] = (dv * TK + pv * 8) * 2;
    }

  // ---- Q fragments, pre-scaled by 1/sqrt(d)*log2(e) ----
  const float SC = 0.08838834764831845f * 1.4426950408889634f;
  short8 qa[8];
  {
    const float* qp = Qb + (size_t)(qbase + l32) * D_DIM + half * 8;
#pragma unroll
    for (int ks = 0; ks < 8; ++ks) {
      float4 a0 = *(const float4*)(qp + ks * 16);
      float4 a1 = *(const float4*)(qp + ks * 16 + 4);
      union { unsigned u[4]; short8 s; } pu;
      pu.u[0] = pk_bf16(a0.x * SC, a0.y * SC);
      pu.u[1] = pk_bf16(a0.z * SC, a0.w * SC);
      pu.u[2] = pk_bf16(a1.x * SC, a1.y * SC);
      pu.u[3] = pk_bf16(a1.z * SC, a1.w * SC);
      qa[ks] = pu.s;
    }
  }

  const f32x16 zf16 = {0.f,0.f,0.f,0.f,0.f,0.f,0.f,0.f,0.f,0.f,0.f,0.f,0.f,0.f,0.f,0.f};
  f32x16 oacc[4];
#pragma unroll
  for (int dt = 0; dt < 4; ++dt) oacc[dt] = zf16;
  float lp[4] = {0.f, 0.f, 0.f, 0.f};

  for (int t = 0; t < 22; ++t) {
    __syncthreads();  // drains DMA(t); all waves done with buf (t+1)&1
    const int cb = t & 1;
    const char* kbc = kbase + cb * 8192;
    const char* vbc = vbase + cb * 8192;

    if (t + 1 < NK) {  // DMA(t+1) flies during compute(t)  [wave-uniform]
      const int nb = cb ^ 1;
#pragma unroll
      for (int cc = 0; cc < 2; ++cc) {
        kgp[cc] += TK * D_DIM;  GLL(kgp[cc], kdst[nb][cc]);
        vgp[cc] += TK;          GLL(vgp[cc], vdst[nb][cc]);
      }
    }

    if (t < NK) {  // [wave-uniform]
      // ---- S^T = K Q^T (regs = keys, cols = q) ----
      f32x16 sacc = zf16;
#pragma unroll
      for (int ks = 0; ks < 8; ++ks) {
        short8 kf = *(const short8*)(kbc + kOff[ks]);
        sacc = __builtin_amdgcn_mfma_f32_32x32x16_bf16(kf, qa[ks], sacc, 0, 0, 0);
      }

      // ---- max-free softmax (scale folded into Q) ----
      float p[16];
#pragma unroll
      for (int r = 0; r < 16; ++r) p[r] = exp2f(sacc[r]);
#pragma unroll
      for (int r = 0; r < 16; ++r) lp[r & 3] += p[r];
      unsigned w[8];
#pragma unroll
      for (int j = 0; j < 8; ++j) w[j] = pk_bf16(p[2 * j], p[2 * j + 1]);

      // ---- P^T -> A-layout via half-swap + O += P V ----
#pragma unroll
      for (int ks2 = 0; ks2 < 2; ++ks2) {
        const int a = ks2 * 4;
        unsigned x0 = (unsigned)__shfl_xor((int)w[a + 0], 32);
        unsigned x1 = (unsigned)__shfl_xor((int)w[a + 1], 32);
        unsigned x2 = (unsigned)__shfl_xor((int)w[a + 2], 32);
        unsigned x3 = (unsigned)__shfl_xor((int)w[a + 3], 32);
        union { unsigned u[4]; short8 s; } pu;
        pu.u[0] = half ? x2 : w[a + 0];
        pu.u[1] = half ? x3 : w[a + 1];
        pu.u[2] = half ? w[a + 2] : x0;
        pu.u[3] = half ? w[a + 3] : x1;
        short8 pf = pu.s;
#pragma unroll
        for (int dt = 0; dt < 4; ++dt) {
          short8 vf = *(const short8*)(vbc + vOff[ks2 * 4 + dt]);
          oacc[dt] = __builtin_amdgcn_mfma_f32_32x32x16_bf16(pf, vf, oacc[dt], 0, 0, 0);
        }
      }
    }
  }

  // ---- per-lane row sum for q = l32 (both halves hold it) ----
  float lt = (lp[0] + lp[1]) + (lp[2] + lp[3]);
  lt += __shfl_xor(lt, 32);

  // ---- 3-way split-K merge: kg1,kg2 -> LDS slots; kg0 adds + stores ----
  __syncthreads();  // all tile reads done; overlay tile space
  float* oslot = (float*)smem;               // 8 slots x 4096 floats
  float* larr  = (float*)(smem + 131072);    // 8 slots x 32 floats
  if (kg > 0) {
    const int s = qg * 2 + (kg - 1);
    float* os = oslot + s * 4096;
#pragma unroll
    for (int reg = 0; reg < 16; ++reg) {
      int row = (reg & 3) + 8 * (reg >> 2) + 4 * half;
#pragma unroll
      for (int dt = 0; dt < 4; ++dt)
        os[row * 128 + dt * 32 + l32] = oacc[dt][reg];
    }
    if (half == 0) larr[s * 32 + l32] = lt;
  }
  __syncthreads();
  if (kg == 0) {
    const float* os0 = oslot + (qg * 2 + 0) * 4096;
    const float* os1 = oslot + (qg * 2 + 1) * 4096;
    float tot = lt + larr[(qg * 2 + 0) * 32 + l32] + larr[(qg * 2 + 1) * 32 + l32];
    float* Ob = O + (size_t)b * S_LEN * D_DIM;
#pragma unroll
    for (int reg = 0; reg < 16; ++reg) {
      int row = (reg & 3) + 8 * (reg >> 2) + 4 * half;
      float linv = 1.f / __shfl(tot, row);
#pragma unroll
      for (int dt = 0; dt < 4; ++dt) {
        int cix = row * 128 + dt * 32 + l32;
        Ob[(size_t)(qbase + row) * D_DIM + dt * 32 + l32] =
            (oacc[dt][reg] + os0[cix] + os1[cix]) * linv;
      }
    }
  }
}

extern "C" void kernel_launch(void* const* d_in, const int* in_sizes, int n_in,
                              void* d_out, int out_size, void* d_ws, size_t ws_size,
                              hipStream_t stream) {
  const float* Q = (const float*)d_in[0];
  const float* K = (const float*)d_in[1];
  const float* V = (const float*)d_in[2];
  float* O = (float*)d_out;
  unsigned short* Kb = (unsigned short*)d_ws;                       // 8.4 MB
  unsigned short* VT = Kb + (size_t)B_N * S_LEN * D_DIM;            // 8.4 MB
  prep_kernel<<<dim3(4096 + 1024), dim3(256), 0, stream>>>(K, V, Kb, VT);
  attn_kernel<<<dim3(256), dim3(768), 0, stream>>>(Q, Kb, VT, O);
}